// Round 16
// baseline (678.445 us; speedup 1.0000x reference)
//
#include <hip/hip_runtime.h>
#include <hip/hip_fp16.h>
#include <stdint.h>

// PyramidGrid (instant-NGP hash grid, simplex interp) forward — R16.
//
// Toll model (R6-R15, 4 linear datapoints): divergent 8B vmem gathers cost
// 4.27-4.29us per M-requests (0.375 req/cyc/CU), invariant to MLP, occupancy,
// hit-rate, and order. Total = toll(117.5M req = 502us) + transpose stream
// (402MB ~= 90us) + tails/gaps. R16 (last structural lever): the hybrid
// blocks (stage L0+L1 fp16 in LDS, compute L0/L1 under level-2 vmem latency)
// move to the END of the conveyor grid -> their staging + LDS work fills the
// level-15 drain tail instead of delaying the conveyor head (R15 had them
// first: 23us serial staging prefix).

constexpr uint32_t kBatch   = 1u << 21;
constexpr uint32_t kQuarter = kBatch / 4u;          // 524288
constexpr size_t   kWsNeed  = (size_t)kBatch * 16u * sizeof(uint32_t);  // 128 MiB

typedef float f32x2 __attribute__((ext_vector_type(2)));
typedef float f32x4 __attribute__((ext_vector_type(4)));

// cumulative row offsets (prev) and pow2 hash masks per level
constexpr uint32_t PREV[16] = {
    0u, 4096u, 36864u, 299008u, 823296u, 1347584u, 1871872u, 2396160u,
    2920448u, 3444736u, 3969024u, 4493312u, 5017600u, 5541888u, 6066176u, 6590464u};
constexpr uint32_t MASK[16] = {
    4095u, 32767u, 262143u, 524287u, 524287u, 524287u, 524287u, 524287u,
    524287u, 524287u, 524287u, 524287u, 524287u, 524287u, 524287u, 524287u};

// Shared per-point math (verified bit-exact vs reference in R1-R15).
// prev may be 0 to obtain table-local indices (LDS levels).
__device__ __forceinline__ void corner_hashes_weights(
    float x0, float x1, float x2, float res, uint32_t mask, uint32_t prev,
    uint32_t& g0, uint32_t& g1, uint32_t& g2, uint32_t& g3,
    float& sa, float& sb, float& sc)
{
    const float fx0 = x0 * res;
    const float fx1 = x1 * res;
    const float fx2 = x2 * res;
    const int i0 = (int)fx0;            // trunc == floor (x >= 0)
    const int i1 = (int)fx1;
    const int i2 = (int)fx2;
    const float f0 = fx0 - (float)i0;   // exact fp32
    const float f1 = fx1 - (float)i1;
    const float f2 = fx2 - (float)i2;

    // stable ascending ranks (== inv_inds of stable argsort)
    const int r0 = (int)(f1 < f0) + (int)(f2 < f0);
    const int r1 = (int)(f0 < f1) + (int)(f2 < f1) + (int)(f0 == f1);
    const int r2 = (int)(f0 < f2) + (int)(f1 < f2) + (int)(f0 == f2) + (int)(f1 == f2);

    sa = fminf(fminf(f0, f1), f2);
    sc = fmaxf(fmaxf(f0, f1), f2);
    sb = __builtin_amdgcn_fmed3f(f0, f1, f2);

    // hash components (uint32 wrap multiply; PRIMES = {1, 2654435761, 805459861})
    const uint32_t A0 = (uint32_t)i0;
    const uint32_t A1 = A0 + 1u;
    const uint32_t B0 = (uint32_t)i1 * 2654435761u;
    const uint32_t B1 = ((uint32_t)i1 + 1u) * 2654435761u;
    const uint32_t C0 = (uint32_t)i2 * 805459861u;
    const uint32_t C1 = ((uint32_t)i2 + 1u) * 805459861u;

    const uint32_t h0 = A1 ^ B1 ^ C1;
    const uint32_t h1 = (r0 >= 1 ? A1 : A0) ^ (r1 >= 1 ? B1 : B0) ^ (r2 >= 1 ? C1 : C0);
    const uint32_t h2 = (r0 >= 2 ? A1 : A0) ^ (r1 >= 2 ? B1 : B0) ^ (r2 >= 2 ? C1 : C0);
    const uint32_t h3 = A0 ^ B0 ^ C0;

    g0 = (h0 & mask) + prev;
    g1 = (h1 & mask) + prev;
    g2 = (h2 & mask) + prev;
    g3 = (h3 & mask) + prev;
}

__device__ __forceinline__ uint32_t pack_f16x2(float x, float y) {
    const __half hx = __float2half(x);   // RNE
    const __half hy = __float2half(y);
    return (uint32_t)__half_as_ushort(hx) | ((uint32_t)__half_as_ushort(hy) << 16);
}

__device__ __forceinline__ float lo_h(uint32_t p) {
    return __half2float(__ushort_as_half((unsigned short)(p & 0xFFFFu)));
}
__device__ __forceinline__ float hi_h(uint32_t p) {
    return __half2float(__ushort_as_half((unsigned short)(p >> 16)));
}

// ---------------- Fused conveyor: levels 3-15 first, hybrid(0,1,2) last ------
// Grid = 13*512 conveyor blocks + 256 hybrid blocks = 6912, all 1024 thr,
// 144KB LDS (1 block/CU, 16 waves — rate-invariant per R13/R15). Conveyor:
// lvl = 3+(bid>>9). Hybrid blocks (bid >= 6656) dispatch LAST -> their L0/L1
// staging + LDS gathers fill the level-15 drain tail; level-2 vmem gathers
// are their only toll contribution.

__global__ __launch_bounds__(1024) void conveyor16(
    const float* __restrict__ in,    // [B,3]
    const float* __restrict__ emb,   // [7114752,2]
    uint32_t* __restrict__ scr)      // [16][B] packed f16x2
{
    __shared__ uint32_t t0[4096];    // level-0 table, fp16x2 (16 KB)
    __shared__ uint32_t t1[32768];   // level-1 table, fp16x2 (128 KB)

    const uint32_t bid = blockIdx.x;

    if (bid < 13u * 512u) {
        // ---- Conveyor level 3..15: fenced 16-gather window ----
        const uint32_t lvl = 3u + (bid >> 9);
        const uint32_t tid = (bid & 511u) * 1024u + threadIdx.x;   // 0..524287

        const float res = (float)(16u << lvl);
        const uint32_t mask = MASK[lvl];
        const uint32_t prev = PREV[lvl];
        uint32_t* slab = scr + (size_t)lvl * kBatch;

        f32x2 e[4][4];
        float sa[4], sb[4], sc[4];
#pragma unroll
        for (int k = 0; k < 4; ++k) {
            const uint32_t b = tid + (uint32_t)k * kQuarter;
            const float x0 = __builtin_nontemporal_load(in + 3u * b + 0u);
            const float x1 = __builtin_nontemporal_load(in + 3u * b + 1u);
            const float x2 = __builtin_nontemporal_load(in + 3u * b + 2u);
            uint32_t g0, g1, g2, g3;
            corner_hashes_weights(x0, x1, x2, res, mask, prev, g0, g1, g2, g3,
                                  sa[k], sb[k], sc[k]);
            e[k][0] = *reinterpret_cast<const f32x2*>(emb + 2u * g0);
            e[k][1] = *reinterpret_cast<const f32x2*>(emb + 2u * g1);
            e[k][2] = *reinterpret_cast<const f32x2*>(emb + 2u * g2);
            e[k][3] = *reinterpret_cast<const f32x2*>(emb + 2u * g3);
        }
        asm volatile(""
            : "+v"(e[0][0]), "+v"(e[0][1]), "+v"(e[0][2]), "+v"(e[0][3]),
              "+v"(e[1][0]), "+v"(e[1][1]), "+v"(e[1][2]), "+v"(e[1][3]),
              "+v"(e[2][0]), "+v"(e[2][1]), "+v"(e[2][2]), "+v"(e[2][3]),
              "+v"(e[3][0]), "+v"(e[3][1]), "+v"(e[3][2]), "+v"(e[3][3]));
#pragma unroll
        for (int k = 0; k < 4; ++k) {
            const float w0 = sa[k];
            const float w1 = sb[k] - sa[k];
            const float w2 = sc[k] - sb[k];
            const float w3 = 1.0f - sc[k];
            const float vx = w0 * e[k][0].x + w1 * e[k][1].x + w2 * e[k][2].x + w3 * e[k][3].x;
            const float vy = w0 * e[k][0].y + w1 * e[k][1].y + w2 * e[k][2].y + w3 * e[k][3].y;
            const uint32_t b = tid + (uint32_t)k * kQuarter;
            __builtin_nontemporal_store(pack_f16x2(vx, vy), slab + b);
        }
    } else {
        // ---- Hybrid block (dispatched last, fills the drain tail) ----
        const uint32_t htid = (bid - 13u * 512u) * 1024u + threadIdx.x;  // 0..262143

        // Stage L0 (rows 0..4095) + L1 (rows 4096..36863) as fp16.
#pragma unroll
        for (uint32_t i = 0u; i < 4u; ++i) {
            const uint32_t r = threadIdx.x + 1024u * i;
            const f32x2 v = *reinterpret_cast<const f32x2*>(emb + 2u * r);
            t0[r] = pack_f16x2(v.x, v.y);
        }
#pragma unroll
        for (uint32_t i = 0u; i < 32u; ++i) {
            const uint32_t r = threadIdx.x + 1024u * i;
            const f32x2 v = *reinterpret_cast<const f32x2*>(emb + 2u * (4096u + r));
            t1[r] = pack_f16x2(v.x, v.y);
        }
        __syncthreads();

#pragma unroll 1
        for (uint32_t k = 0u; k < 8u; ++k) {
            const uint32_t b = htid + k * 262144u;
            const float x0 = __builtin_nontemporal_load(in + 3u * b + 0u);
            const float x1 = __builtin_nontemporal_load(in + 3u * b + 1u);
            const float x2 = __builtin_nontemporal_load(in + 3u * b + 2u);

            // Level 2 (vmem) first: res=64, mask=262143, prev=36864.
            uint32_t g0, g1, g2, g3;
            float sa2, sb2, sc2;
            corner_hashes_weights(x0, x1, x2, 64.0f, 262143u, 36864u,
                                  g0, g1, g2, g3, sa2, sb2, sc2);
            f32x2 e2a = *reinterpret_cast<const f32x2*>(emb + 2u * g0);
            f32x2 e2b = *reinterpret_cast<const f32x2*>(emb + 2u * g1);
            f32x2 e2c = *reinterpret_cast<const f32x2*>(emb + 2u * g2);
            f32x2 e2d = *reinterpret_cast<const f32x2*>(emb + 2u * g3);

            // Level 0 from LDS.
            {
                uint32_t l0, l1, l2, l3;
                float sa, sb, sc;
                corner_hashes_weights(x0, x1, x2, 16.0f, 4095u, 0u,
                                      l0, l1, l2, l3, sa, sb, sc);
                const uint32_t p0 = t0[l0], p1 = t0[l1], p2 = t0[l2], p3 = t0[l3];
                const float w0 = sa, w1 = sb - sa, w2 = sc - sb, w3 = 1.0f - sc;
                const float vx = w0 * lo_h(p0) + w1 * lo_h(p1) + w2 * lo_h(p2) + w3 * lo_h(p3);
                const float vy = w0 * hi_h(p0) + w1 * hi_h(p1) + w2 * hi_h(p2) + w3 * hi_h(p3);
                __builtin_nontemporal_store(pack_f16x2(vx, vy), scr + b);
            }
            // Level 1 from LDS.
            {
                uint32_t l0, l1, l2, l3;
                float sa, sb, sc;
                corner_hashes_weights(x0, x1, x2, 32.0f, 32767u, 0u,
                                      l0, l1, l2, l3, sa, sb, sc);
                const uint32_t p0 = t1[l0], p1 = t1[l1], p2 = t1[l2], p3 = t1[l3];
                const float w0 = sa, w1 = sb - sa, w2 = sc - sb, w3 = 1.0f - sc;
                const float vx = w0 * lo_h(p0) + w1 * lo_h(p1) + w2 * lo_h(p2) + w3 * lo_h(p3);
                const float vy = w0 * hi_h(p0) + w1 * hi_h(p1) + w2 * hi_h(p2) + w3 * hi_h(p3);
                __builtin_nontemporal_store(pack_f16x2(vx, vy), scr + (size_t)kBatch + b);
            }

            // Fence level-2 loads, combine, store.
            asm volatile("" : "+v"(e2a), "+v"(e2b), "+v"(e2c), "+v"(e2d));
            const float w0 = sa2, w1 = sb2 - sa2, w2 = sc2 - sb2, w3 = 1.0f - sc2;
            const float vx = w0 * e2a.x + w1 * e2b.x + w2 * e2c.x + w3 * e2d.x;
            const float vy = w0 * e2a.y + w1 * e2b.y + w2 * e2c.y + w3 * e2d.y;
            __builtin_nontemporal_store(pack_f16x2(vx, vy), scr + (size_t)2u * kBatch + b);
        }
    }
}

// Assemble all 16 level slabs -> one contiguous 128B line per point.
__global__ __launch_bounds__(256) void transpose16(
    const uint32_t* __restrict__ scr,  // [16][B] packed f16x2
    float* __restrict__ out)           // [B,32]
{
    const uint32_t b = blockIdx.x * 256u + threadIdx.x;

    uint32_t p[16];
#pragma unroll
    for (int l = 0; l < 16; ++l)
        p[l] = __builtin_nontemporal_load(scr + (size_t)l * kBatch + b);

    float* o = out + (size_t)b * 32u;
#pragma unroll
    for (int q = 0; q < 8; ++q) {
        f32x4 t;
        t.x = lo_h(p[2 * q + 0]);
        t.y = hi_h(p[2 * q + 0]);
        t.z = lo_h(p[2 * q + 1]);
        t.w = hi_h(p[2 * q + 1]);
        *reinterpret_cast<f32x4*>(o + 4 * q) = t;
    }
}

// ---------------- Fallback: monolithic (if ws too small) ----------------

__global__ __launch_bounds__(256) void pyramid_fwd_mono(
    const float* __restrict__ in,
    const float* __restrict__ emb,
    float* __restrict__ out)
{
    const uint32_t b = blockIdx.x * 256u + threadIdx.x;
    const float x0 = in[3u * b + 0u];
    const float x1 = in[3u * b + 1u];
    const float x2 = in[3u * b + 2u];

#pragma unroll
    for (int g = 0; g < 2; ++g) {
        float o8[16];
#pragma unroll
        for (int k = 0; k < 8; ++k) {
            const int lvl = g * 8 + k;
            const float res = (float)(16 << lvl);
            uint32_t g0, g1, g2, g3;
            float sa, sb, sc;
            corner_hashes_weights(x0, x1, x2, res, MASK[lvl], PREV[lvl],
                                  g0, g1, g2, g3, sa, sb, sc);
            const f32x2 e0 = *reinterpret_cast<const f32x2*>(emb + 2u * g0);
            const f32x2 e1 = *reinterpret_cast<const f32x2*>(emb + 2u * g1);
            const f32x2 e2 = *reinterpret_cast<const f32x2*>(emb + 2u * g2);
            const f32x2 e3 = *reinterpret_cast<const f32x2*>(emb + 2u * g3);
            const float w0 = sa, w1 = sb - sa, w2 = sc - sb, w3 = 1.0f - sc;
            o8[2 * k + 0] = w0 * e0.x + w1 * e1.x + w2 * e2.x + w3 * e3.x;
            o8[2 * k + 1] = w0 * e0.y + w1 * e1.y + w2 * e2.y + w3 * e3.y;
        }
        f32x4* o = reinterpret_cast<f32x4*>(out + (size_t)b * 32u + (size_t)g * 16u);
#pragma unroll
        for (int q = 0; q < 4; ++q) {
            f32x4 v;
            v.x = o8[4 * q + 0];
            v.y = o8[4 * q + 1];
            v.z = o8[4 * q + 2];
            v.w = o8[4 * q + 3];
            o[q] = v;
        }
    }
}

// ---------------- Launch ----------------

extern "C" void kernel_launch(void* const* d_in, const int* in_sizes, int n_in,
                              void* d_out, int out_size, void* d_ws, size_t ws_size,
                              hipStream_t stream) {
    const float* in  = (const float*)d_in[0];
    const float* emb = (const float*)d_in[1];
    float* out = (float*)d_out;

    if (ws_size >= kWsNeed) {
        uint32_t* scr = (uint32_t*)d_ws;
        hipLaunchKernelGGL(conveyor16, dim3(13u * 512u + 256u), dim3(1024u), 0, stream,
                           in, emb, scr);
        hipLaunchKernelGGL(transpose16, dim3(kBatch / 256u), dim3(256u), 0, stream,
                           scr, out);
    } else {
        hipLaunchKernelGGL(pyramid_fwd_mono, dim3(kBatch / 256u), dim3(256u), 0, stream,
                           in, emb, out);
    }
}

// Round 17
// 661.951 us; speedup vs baseline: 1.0249x; 1.0249x over previous
//
#include <hip/hip_runtime.h>
#include <hip/hip_fp16.h>
#include <stdint.h>

// PyramidGrid (instant-NGP hash grid, simplex interp) forward — R17 (= R14,
// the best-measured structure, 663us; R15/R16 fusion variants were 668/678).
//
// Final model (R6-R16, 5 linear datapoints): divergent 8B vmem gathers cost
// 4.27-4.29us per M-requests (0.375 req/cyc/CU), invariant to MLP, occupancy,
// hit-rate, order, and kernel packing; hits cost the same as misses (the wall
// is the per-CU TA/TCP request pipe). The only bypass is the LDS pipe:
// levels 0+1 (144KB as fp16) live there; level 2+ must pay the toll.
// Floor: 14 levels x 8.39M req x 4.27us/M = 501us toll + 88us transpose
// stream + ~25us staging/gaps ~= 615us. This kernel: 663us (+8%).
//
// Structure: hybrid012 (256 blk x 1024 thr, 144KB LDS: L0+L1 fp16 tables,
// level-2 vmem gathers hidden under LDS work) -> gather13 (dispatch-conveyor
// level phasing, lvl = 3+(bid>>11), each 4MB table L2-resident during its
// phase) -> transpose16 (fp16 scratch -> one 128B fp32 line per point).

constexpr uint32_t kBatch   = 1u << 21;
constexpr size_t   kWsNeed  = (size_t)kBatch * 16u * sizeof(uint32_t);  // 128 MiB

typedef float f32x2 __attribute__((ext_vector_type(2)));
typedef float f32x4 __attribute__((ext_vector_type(4)));

// cumulative row offsets (prev) and pow2 hash masks per level
constexpr uint32_t PREV[16] = {
    0u, 4096u, 36864u, 299008u, 823296u, 1347584u, 1871872u, 2396160u,
    2920448u, 3444736u, 3969024u, 4493312u, 5017600u, 5541888u, 6066176u, 6590464u};
constexpr uint32_t MASK[16] = {
    4095u, 32767u, 262143u, 524287u, 524287u, 524287u, 524287u, 524287u,
    524287u, 524287u, 524287u, 524287u, 524287u, 524287u, 524287u, 524287u};

// Shared per-point math (verified bit-exact vs reference in R1-R16).
// prev may be 0 to obtain table-local indices (LDS levels).
__device__ __forceinline__ void corner_hashes_weights(
    float x0, float x1, float x2, float res, uint32_t mask, uint32_t prev,
    uint32_t& g0, uint32_t& g1, uint32_t& g2, uint32_t& g3,
    float& sa, float& sb, float& sc)
{
    const float fx0 = x0 * res;
    const float fx1 = x1 * res;
    const float fx2 = x2 * res;
    const int i0 = (int)fx0;            // trunc == floor (x >= 0)
    const int i1 = (int)fx1;
    const int i2 = (int)fx2;
    const float f0 = fx0 - (float)i0;   // exact fp32
    const float f1 = fx1 - (float)i1;
    const float f2 = fx2 - (float)i2;

    // stable ascending ranks (== inv_inds of stable argsort)
    const int r0 = (int)(f1 < f0) + (int)(f2 < f0);
    const int r1 = (int)(f0 < f1) + (int)(f2 < f1) + (int)(f0 == f1);
    const int r2 = (int)(f0 < f2) + (int)(f1 < f2) + (int)(f0 == f2) + (int)(f1 == f2);

    sa = fminf(fminf(f0, f1), f2);
    sc = fmaxf(fmaxf(f0, f1), f2);
    sb = __builtin_amdgcn_fmed3f(f0, f1, f2);

    // hash components (uint32 wrap multiply; PRIMES = {1, 2654435761, 805459861})
    const uint32_t A0 = (uint32_t)i0;
    const uint32_t A1 = A0 + 1u;
    const uint32_t B0 = (uint32_t)i1 * 2654435761u;
    const uint32_t B1 = ((uint32_t)i1 + 1u) * 2654435761u;
    const uint32_t C0 = (uint32_t)i2 * 805459861u;
    const uint32_t C1 = ((uint32_t)i2 + 1u) * 805459861u;

    const uint32_t h0 = A1 ^ B1 ^ C1;
    const uint32_t h1 = (r0 >= 1 ? A1 : A0) ^ (r1 >= 1 ? B1 : B0) ^ (r2 >= 1 ? C1 : C0);
    const uint32_t h2 = (r0 >= 2 ? A1 : A0) ^ (r1 >= 2 ? B1 : B0) ^ (r2 >= 2 ? C1 : C0);
    const uint32_t h3 = A0 ^ B0 ^ C0;

    g0 = (h0 & mask) + prev;
    g1 = (h1 & mask) + prev;
    g2 = (h2 & mask) + prev;
    g3 = (h3 & mask) + prev;
}

__device__ __forceinline__ uint32_t pack_f16x2(float x, float y) {
    const __half hx = __float2half(x);   // RNE
    const __half hy = __float2half(y);
    return (uint32_t)__half_as_ushort(hx) | ((uint32_t)__half_as_ushort(hy) << 16);
}

__device__ __forceinline__ float lo_h(uint32_t p) {
    return __half2float(__ushort_as_half((unsigned short)(p & 0xFFFFu)));
}
__device__ __forceinline__ float hi_h(uint32_t p) {
    return __half2float(__ushort_as_half((unsigned short)(p >> 16)));
}

// ---------------- Hybrid kernel: levels 0+1 from LDS, level 2 on vmem ----------
// 256 blocks x 1024 threads, 144KB LDS (1 block/CU, 16 waves). Each thread: 8
// points; per point issue level-2 vmem gathers first, do levels 0+1 from LDS
// under that latency, then combine level 2.

__global__ __launch_bounds__(1024) void hybrid012(
    const float* __restrict__ in,    // [B,3]
    const float* __restrict__ emb,   // [7114752,2]
    uint32_t* __restrict__ scr)      // [16][B] packed f16x2
{
    __shared__ uint32_t t0[4096];    // level-0 table, fp16x2 (16 KB)
    __shared__ uint32_t t1[32768];   // level-1 table, fp16x2 (128 KB)

    const uint32_t t = threadIdx.x;

    // Stage level 0 (rows 0..4095) and level 1 (rows 4096..36863), coalesced.
#pragma unroll
    for (uint32_t i = 0u; i < 4u; ++i) {
        const uint32_t r = t + 1024u * i;
        const f32x2 v = *reinterpret_cast<const f32x2*>(emb + 2u * r);
        t0[r] = pack_f16x2(v.x, v.y);
    }
#pragma unroll
    for (uint32_t i = 0u; i < 32u; ++i) {
        const uint32_t r = t + 1024u * i;
        const f32x2 v = *reinterpret_cast<const f32x2*>(emb + 2u * (4096u + r));
        t1[r] = pack_f16x2(v.x, v.y);
    }
    __syncthreads();

    const uint32_t tid = blockIdx.x * 1024u + t;   // 0..262143

#pragma unroll 1
    for (uint32_t k = 0u; k < 8u; ++k) {
        const uint32_t b = tid + k * 262144u;
        const float x0 = __builtin_nontemporal_load(in + 3u * b + 0u);
        const float x1 = __builtin_nontemporal_load(in + 3u * b + 1u);
        const float x2 = __builtin_nontemporal_load(in + 3u * b + 2u);

        // Level 2 (vmem) FIRST: res=64, mask=262143, prev=36864.
        uint32_t g0, g1, g2, g3;
        float sa2, sb2, sc2;
        corner_hashes_weights(x0, x1, x2, 64.0f, 262143u, 36864u,
                              g0, g1, g2, g3, sa2, sb2, sc2);
        f32x2 e2a = *reinterpret_cast<const f32x2*>(emb + 2u * g0);
        f32x2 e2b = *reinterpret_cast<const f32x2*>(emb + 2u * g1);
        f32x2 e2c = *reinterpret_cast<const f32x2*>(emb + 2u * g2);
        f32x2 e2d = *reinterpret_cast<const f32x2*>(emb + 2u * g3);

        // Level 0 from LDS: res=16, mask=4095, local idx.
        {
            uint32_t l0, l1, l2, l3;
            float sa, sb, sc;
            corner_hashes_weights(x0, x1, x2, 16.0f, 4095u, 0u,
                                  l0, l1, l2, l3, sa, sb, sc);
            const uint32_t p0 = t0[l0], p1 = t0[l1], p2 = t0[l2], p3 = t0[l3];
            const float w0 = sa, w1 = sb - sa, w2 = sc - sb, w3 = 1.0f - sc;
            const float vx = w0 * lo_h(p0) + w1 * lo_h(p1) + w2 * lo_h(p2) + w3 * lo_h(p3);
            const float vy = w0 * hi_h(p0) + w1 * hi_h(p1) + w2 * hi_h(p2) + w3 * hi_h(p3);
            __builtin_nontemporal_store(pack_f16x2(vx, vy), scr + b);
        }
        // Level 1 from LDS: res=32, mask=32767, local idx.
        {
            uint32_t l0, l1, l2, l3;
            float sa, sb, sc;
            corner_hashes_weights(x0, x1, x2, 32.0f, 32767u, 0u,
                                  l0, l1, l2, l3, sa, sb, sc);
            const uint32_t p0 = t1[l0], p1 = t1[l1], p2 = t1[l2], p3 = t1[l3];
            const float w0 = sa, w1 = sb - sa, w2 = sc - sb, w3 = 1.0f - sc;
            const float vx = w0 * lo_h(p0) + w1 * lo_h(p1) + w2 * lo_h(p2) + w3 * lo_h(p3);
            const float vy = w0 * hi_h(p0) + w1 * hi_h(p1) + w2 * hi_h(p2) + w3 * hi_h(p3);
            __builtin_nontemporal_store(pack_f16x2(vx, vy), scr + (size_t)kBatch + b);
        }

        // Fence level-2 loads, combine, store.
        asm volatile("" : "+v"(e2a), "+v"(e2b), "+v"(e2c), "+v"(e2d));
        const float w0 = sa2, w1 = sb2 - sa2, w2 = sc2 - sb2, w3 = 1.0f - sc2;
        const float vx = w0 * e2a.x + w1 * e2b.x + w2 * e2c.x + w3 * e2d.x;
        const float vy = w0 * e2a.y + w1 * e2b.y + w2 * e2c.y + w3 * e2d.y;
        __builtin_nontemporal_store(pack_f16x2(vx, vy), scr + (size_t)2u * kBatch + b);
    }
}

// ---------------- Conveyor gather: levels 3..15 ----------------
// blockIdx.x in [0, 13*2048): lvl = 3 + (bid >> 11). No LDS -> 8 blocks/CU,
// one level's 2048 blocks ~= co-resident capacity -> L2-resident table phases.

__global__ __launch_bounds__(256) void gather13(
    const float* __restrict__ in,    // [B,3]
    const float* __restrict__ emb,   // [7114752,2]
    uint32_t* __restrict__ scr)      // [16][B] packed f16x2
{
    const uint32_t bid  = blockIdx.x;
    const uint32_t lvl  = 3u + (bid >> 11);
    const uint32_t tid  = (bid & 2047u) * 256u + threadIdx.x;
    const uint32_t quarter = kBatch / 4u;

    const float res = (float)(16u << lvl);
    const uint32_t mask = MASK[lvl];
    const uint32_t prev = PREV[lvl];
    uint32_t* slab = scr + (size_t)lvl * kBatch;

    f32x2 e[4][4];
    float sa[4], sb[4], sc[4];

#pragma unroll
    for (int k = 0; k < 4; ++k) {
        const uint32_t b = tid + (uint32_t)k * quarter;
        const float x0 = __builtin_nontemporal_load(in + 3u * b + 0u);
        const float x1 = __builtin_nontemporal_load(in + 3u * b + 1u);
        const float x2 = __builtin_nontemporal_load(in + 3u * b + 2u);
        uint32_t g0, g1, g2, g3;
        corner_hashes_weights(x0, x1, x2, res, mask, prev, g0, g1, g2, g3,
                              sa[k], sb[k], sc[k]);
        e[k][0] = *reinterpret_cast<const f32x2*>(emb + 2u * g0);
        e[k][1] = *reinterpret_cast<const f32x2*>(emb + 2u * g1);
        e[k][2] = *reinterpret_cast<const f32x2*>(emb + 2u * g2);
        e[k][3] = *reinterpret_cast<const f32x2*>(emb + 2u * g3);
    }

    // Keep all 16 loads in flight (R6-proven data-dependency fence).
    asm volatile(""
        : "+v"(e[0][0]), "+v"(e[0][1]), "+v"(e[0][2]), "+v"(e[0][3]),
          "+v"(e[1][0]), "+v"(e[1][1]), "+v"(e[1][2]), "+v"(e[1][3]),
          "+v"(e[2][0]), "+v"(e[2][1]), "+v"(e[2][2]), "+v"(e[2][3]),
          "+v"(e[3][0]), "+v"(e[3][1]), "+v"(e[3][2]), "+v"(e[3][3]));

#pragma unroll
    for (int k = 0; k < 4; ++k) {
        const float w0 = sa[k];
        const float w1 = sb[k] - sa[k];
        const float w2 = sc[k] - sb[k];
        const float w3 = 1.0f - sc[k];
        const float vx = w0 * e[k][0].x + w1 * e[k][1].x + w2 * e[k][2].x + w3 * e[k][3].x;
        const float vy = w0 * e[k][0].y + w1 * e[k][1].y + w2 * e[k][2].y + w3 * e[k][3].y;
        const uint32_t b = tid + (uint32_t)k * quarter;
        __builtin_nontemporal_store(pack_f16x2(vx, vy), slab + b);
    }
}

// Assemble all 16 level slabs -> one contiguous 128B line per point.
__global__ __launch_bounds__(256) void transpose16(
    const uint32_t* __restrict__ scr,  // [16][B] packed f16x2
    float* __restrict__ out)           // [B,32]
{
    const uint32_t b = blockIdx.x * 256u + threadIdx.x;

    uint32_t p[16];
#pragma unroll
    for (int l = 0; l < 16; ++l)
        p[l] = __builtin_nontemporal_load(scr + (size_t)l * kBatch + b);

    float* o = out + (size_t)b * 32u;
#pragma unroll
    for (int q = 0; q < 8; ++q) {
        f32x4 t;
        t.x = lo_h(p[2 * q + 0]);
        t.y = hi_h(p[2 * q + 0]);
        t.z = lo_h(p[2 * q + 1]);
        t.w = hi_h(p[2 * q + 1]);
        *reinterpret_cast<f32x4*>(o + 4 * q) = t;
    }
}

// ---------------- Fallback: monolithic (if ws too small) ----------------

__global__ __launch_bounds__(256) void pyramid_fwd_mono(
    const float* __restrict__ in,
    const float* __restrict__ emb,
    float* __restrict__ out)
{
    const uint32_t b = blockIdx.x * 256u + threadIdx.x;
    const float x0 = in[3u * b + 0u];
    const float x1 = in[3u * b + 1u];
    const float x2 = in[3u * b + 2u];

#pragma unroll
    for (int g = 0; g < 2; ++g) {
        float o8[16];
#pragma unroll
        for (int k = 0; k < 8; ++k) {
            const int lvl = g * 8 + k;
            const float res = (float)(16 << lvl);
            uint32_t g0, g1, g2, g3;
            float sa, sb, sc;
            corner_hashes_weights(x0, x1, x2, res, MASK[lvl], PREV[lvl],
                                  g0, g1, g2, g3, sa, sb, sc);
            const f32x2 e0 = *reinterpret_cast<const f32x2*>(emb + 2u * g0);
            const f32x2 e1 = *reinterpret_cast<const f32x2*>(emb + 2u * g1);
            const f32x2 e2 = *reinterpret_cast<const f32x2*>(emb + 2u * g2);
            const f32x2 e3 = *reinterpret_cast<const f32x2*>(emb + 2u * g3);
            const float w0 = sa, w1 = sb - sa, w2 = sc - sb, w3 = 1.0f - sc;
            o8[2 * k + 0] = w0 * e0.x + w1 * e1.x + w2 * e2.x + w3 * e3.x;
            o8[2 * k + 1] = w0 * e0.y + w1 * e1.y + w2 * e2.y + w3 * e3.y;
        }
        f32x4* o = reinterpret_cast<f32x4*>(out + (size_t)b * 32u + (size_t)g * 16u);
#pragma unroll
        for (int q = 0; q < 4; ++q) {
            f32x4 v;
            v.x = o8[4 * q + 0];
            v.y = o8[4 * q + 1];
            v.z = o8[4 * q + 2];
            v.w = o8[4 * q + 3];
            o[q] = v;
        }
    }
}

// ---------------- Launch ----------------

extern "C" void kernel_launch(void* const* d_in, const int* in_sizes, int n_in,
                              void* d_out, int out_size, void* d_ws, size_t ws_size,
                              hipStream_t stream) {
    const float* in  = (const float*)d_in[0];
    const float* emb = (const float*)d_in[1];
    float* out = (float*)d_out;

    if (ws_size >= kWsNeed) {
        uint32_t* scr = (uint32_t*)d_ws;
        hipLaunchKernelGGL(hybrid012, dim3(256u), dim3(1024u), 0, stream, in, emb, scr);
        hipLaunchKernelGGL(gather13, dim3(13u * 2048u), dim3(256u), 0, stream, in, emb, scr);
        hipLaunchKernelGGL(transpose16, dim3(kBatch / 256u), dim3(256u), 0, stream, scr, out);
    } else {
        hipLaunchKernelGGL(pyramid_fwd_mono, dim3(kBatch / 256u), dim3(256u), 0, stream,
                           in, emb, out);
    }
}